// Round 1
// baseline (961.325 us; speedup 1.0000x reference)
//
#include <hip/hip_runtime.h>
#include <math.h>

#define B_    4
#define CIN   16
#define COUT  32
#define DD    32
#define HH    128
#define WW    128
#define KK    3
#define EPSF  1e-5f

#define TD 4
#define TH 8
#define TW 8
#define ID (TD + 2)
#define IH (TH + 2)
#define IW (TW + 2)
#define XS_SIZE (CIN * ID * IH * IW)   // 16*6*10*10 = 9600 floats = 38.4 KB

#define W_ELEMS (COUT * CIN * KK * KK * KK)  // 13824

// Transpose weights from [co][ci][kd][kh][kw] to [ci*27+kd*9+kh*3+kw][co]
// so that per-(ci,kd,kh) the 3*32 weights are contiguous -> s_load_dwordx16.
__global__ void transpose_w_kernel(const float* __restrict__ w, float* __restrict__ wt) {
    int i = blockIdx.x * 256 + threadIdx.x;
    if (i < W_ELEMS) {
        int idx = i >> 5;        // /COUT
        int co  = i & 31;        // %COUT
        wt[i] = w[co * (CIN * 27) + idx];
    }
}

template <bool TR>
__launch_bounds__(256)
__global__ void conv_fused_kernel(const float* __restrict__ x,
                                  const float* __restrict__ w,
                                  const float* __restrict__ bias,
                                  const float* __restrict__ mult,
                                  float* __restrict__ out) {
    __shared__ float xs[XS_SIZE];

    const int tid = threadIdx.x;
    const int wt_ = blockIdx.x & 15;          // W/TW = 16
    const int ht_ = blockIdx.x >> 4;          // H/TH = 16
    const int dt_ = blockIdx.y;               // D/TD = 8
    const int b   = blockIdx.z;               // B = 4
    const int w0 = wt_ * TW, h0 = ht_ * TH, d0 = dt_ * TD;

    // ---- stage input halo tile to LDS (zero-padded) ----
    const float* xb = x + (size_t)b * CIN * DD * HH * WW;
    for (int i = tid; i < XS_SIZE; i += 256) {
        int ci = i / (ID * IH * IW);
        int r  = i % (ID * IH * IW);
        int zd = r / (IH * IW);
        int r2 = r % (IH * IW);
        int yh = r2 / IW;
        int xw = r2 % IW;
        int d = d0 + zd - 1;
        int h = h0 + yh - 1;
        int ww = w0 + xw - 1;
        float v = 0.0f;
        if ((unsigned)d < DD && (unsigned)h < HH && (unsigned)ww < WW)
            v = xb[((size_t)ci * DD + d) * (HH * WW) + h * WW + ww];
        xs[i] = v;
    }
    __syncthreads();

    const int tw = tid & 7;
    const int th = (tid >> 3) & 7;
    const int td = tid >> 6;

    float acc[COUT];
    #pragma unroll
    for (int co = 0; co < COUT; ++co) acc[co] = 0.0f;

    // ---- main conv loop: per (ci,kd,kh): 3 LDS reads, 96 FMAs w/ scalar weights ----
    #pragma unroll 1
    for (int ci = 0; ci < CIN; ++ci) {
        #pragma unroll
        for (int kd = 0; kd < KK; ++kd) {
            #pragma unroll
            for (int kh = 0; kh < KK; ++kh) {
                const float* xrow = &xs[((ci * ID + td + kd) * IH + th + kh) * IW + tw];
                const float x0 = xrow[0];
                const float x1 = xrow[1];
                const float x2 = xrow[2];
                const int idx = ci * 27 + kd * 9 + kh * 3;
                if (TR) {
                    const float* wr = w + idx * COUT;  // [kw][co], contiguous 96 floats
                    #pragma unroll
                    for (int co = 0; co < COUT; ++co) {
                        acc[co] += x0 * wr[co];
                        acc[co] += x1 * wr[COUT + co];
                        acc[co] += x2 * wr[2 * COUT + co];
                    }
                } else {
                    #pragma unroll
                    for (int co = 0; co < COUT; ++co) {
                        const float* wr = w + co * (CIN * 27) + idx;
                        acc[co] += x0 * wr[0];
                        acc[co] += x1 * wr[1];
                        acc[co] += x2 * wr[2];
                    }
                }
            }
        }
    }

    // ---- fused epilogue: bias, multiplier, pseudo-norm, clip, channel max ----
    const float cfac = 1.0f - 1.0f / (float)COUT;
    float best = -INFINITY;
    #pragma unroll
    for (int co = 0; co < COUT; ++co) {
        const float m = mult[co];
        const float y = (acc[co] + bias[co]) * m;
        const float t = y * cfac;
        const float nrm = t / sqrtf(fabsf(t) + EPSF);
        const float c = fminf(fmaxf(nrm, -1.0f), 1.0f);
        best = fmaxf(best, c * m);
    }

    out[((size_t)(b * DD + d0 + td) * HH + (h0 + th)) * WW + (w0 + tw)] = best;
}

extern "C" void kernel_launch(void* const* d_in, const int* in_sizes, int n_in,
                              void* d_out, int out_size, void* d_ws, size_t ws_size,
                              hipStream_t stream) {
    const float* x    = (const float*)d_in[0];
    const float* wgt  = (const float*)d_in[1];
    const float* bias = (const float*)d_in[2];
    const float* mult = (const float*)d_in[3];
    float* out = (float*)d_out;

    dim3 grid((WW / TW) * (HH / TH), DD / TD, B_);
    dim3 block(256, 1, 1);

    if (ws_size >= (size_t)W_ELEMS * sizeof(float)) {
        float* wt = (float*)d_ws;
        transpose_w_kernel<<<(W_ELEMS + 255) / 256, 256, 0, stream>>>(wgt, wt);
        conv_fused_kernel<true><<<grid, block, 0, stream>>>(x, wt, bias, mult, out);
    } else {
        conv_fused_kernel<false><<<grid, block, 0, stream>>>(x, wgt, bias, mult, out);
    }
}

// Round 2
// 389.620 us; speedup vs baseline: 2.4673x; 2.4673x over previous
//
#include <hip/hip_runtime.h>
#include <math.h>

// ---------------- problem constants ----------------
#define B_    4
#define CIN   16
#define COUT  32
#define DD    32
#define HH    128
#define WW    128
#define EPSF  1e-5f

typedef _Float16 half8 __attribute__((ext_vector_type(8)));
typedef float f32x16 __attribute__((ext_vector_type(16)));
typedef unsigned int u32x4 __attribute__((ext_vector_type(4)));

// ws layout: [w_frag: 27*2*64*8 halfs][x_t: b,d,h,pc(4),w,8 halfs]
#define WFRAG_HALFS (27 * 2 * 64 * 8)                       // 27648 halfs = 55296 B
#define XT_HALFS    ((size_t)B_ * DD * HH * 4 * WW * 8)     // 67,108,864 halfs = 128 MiB
#define WS_NEEDED   ((size_t)WFRAG_HALFS * 2 + XT_HALFS * 2)

// =====================================================================
// pre-pass 1: weight fragments.
// w_frag[tap][plane][lane][j] = plane(w[co][ci][tap]), co=lane&31, ci=(lane>>5)*8+j
// plane0 = f16 hi, plane1 = f16 residual. One 16B chunk per thread.
// =====================================================================
__global__ void prep_w(const float* __restrict__ w, _Float16* __restrict__ wf) {
    int t = blockIdx.x * 256 + threadIdx.x;
    if (t >= 27 * 2 * 64) return;
    int lane = t & 63;
    int pp = t >> 6;
    int tap = pp >> 1, plane = pp & 1;
    int co = lane & 31, cih = lane >> 5;
    half8 o;
    #pragma unroll
    for (int j = 0; j < 8; ++j) {
        int ci = cih * 8 + j;
        float v = w[(co * CIN + ci) * 27 + tap];
        _Float16 hi = (_Float16)v;
        o[j] = plane ? (_Float16)(v - (float)hi) : hi;
    }
    *(half8*)(wf + (size_t)t * 8) = o;
}

// =====================================================================
// pre-pass 2: x -> channels-last split-f16.
// x_t[b][d][h][pc][w][8] halfs, pc = plane*2 + cihalf  (ci = cihalf*8 + j)
// =====================================================================
__global__ void prep_x(const float* __restrict__ x, _Float16* __restrict__ xt) {
    int sp = blockIdx.x * 256 + threadIdx.x;     // 2,097,152 total (exact grid)
    int w = sp & 127;
    int h = (sp >> 7) & 127;
    int d = (sp >> 14) & 31;
    int b = sp >> 19;
    half8 hi0, hi1, lo0, lo1;
    #pragma unroll
    for (int j = 0; j < 8; ++j) {
        float v0 = x[(((size_t)(b * CIN + j)) * DD + d) * (HH * WW) + h * WW + w];
        float v1 = x[(((size_t)(b * CIN + 8 + j)) * DD + d) * (HH * WW) + h * WW + w];
        _Float16 h0 = (_Float16)v0;
        _Float16 h1 = (_Float16)v1;
        hi0[j] = h0; lo0[j] = (_Float16)(v0 - (float)h0);
        hi1[j] = h1; lo1[j] = (_Float16)(v1 - (float)h1);
    }
    size_t base = ((((size_t)(b * DD + d) * HH + h) * 4 + 0) * WW + w) * 8;
    size_t pcs = (size_t)WW * 8;  // pc stride in halfs
    *(half8*)(xt + base + 0 * pcs) = hi0;
    *(half8*)(xt + base + 1 * pcs) = hi1;
    *(half8*)(xt + base + 2 * pcs) = lo0;
    *(half8*)(xt + base + 3 * pcs) = lo1;
}

// =====================================================================
// main conv kernel: implicit GEMM, mfma_f32_32x32x16_f16, split-f16 x3.
// Block tile: (TD=2, TH=4, TW=32) outputs; 4 waves, each wave: d=td, two
// h-rows (th2+f), 32 w. Halo in LDS: [pc(4)][sp(4*6*34)][8] halfs = 52224 B.
// =====================================================================
#define IDh 4
#define IHh 6
#define IWh 34
#define SPN (IDh * IHh * IWh)     // 816
#define XS_HALFS (4 * SPN * 8)    // 26112 halfs = 52224 B
#define NCHUNK (4 * 24 * IWh)     // 3264 16B chunks

__launch_bounds__(256, 3)
__global__ void conv_mfma(const _Float16* __restrict__ xt,
                          const _Float16* __restrict__ wf,
                          const float* __restrict__ bias,
                          const float* __restrict__ mult,
                          float* __restrict__ out) {
    __shared__ _Float16 xs[XS_HALFS];

    const int tid  = threadIdx.x;
    const int lane = tid & 63;
    const int wid  = tid >> 6;

    const int wt = blockIdx.x & 3;     // W/32
    const int ht = blockIdx.x >> 2;    // H/4
    const int dt = blockIdx.y;         // D/2
    const int b  = blockIdx.z;
    const int w0 = wt * 32, h0 = ht * 4, d0 = dt * 2;

    // ---- stage halo (linear LDS writes, coalesced 16B global reads) ----
    for (int c = tid; c < NCHUNK; c += 256) {
        int pc  = c / (24 * IWh);
        int rc  = c - pc * (24 * IWh);
        int r24 = rc / IWh;                 // zd*6 + yh
        int col = rc - r24 * IWh;
        int zd = r24 / IHh, yh = r24 - zd * IHh;
        int d = d0 + zd - 1, h = h0 + yh - 1, w = w0 + col - 1;
        u32x4 v = {};
        if ((unsigned)d < DD && (unsigned)h < HH && (unsigned)w < WW) {
            const _Float16* g = xt + ((((size_t)(b * DD + d) * HH + h) * 4 + pc) * WW + w) * 8;
            v = *(const u32x4*)g;
        }
        *(u32x4*)&xs[(size_t)c * 8] = v;
    }
    __syncthreads();

    const int td  = wid >> 1;
    const int th2 = (wid & 1) * 2;
    const int cih = lane >> 5;
    const int wl  = lane & 31;

    f32x16 acc0 = {};
    f32x16 acc1 = {};

    // per-lane A bases (halfs): plane p at pc = p*2+cih; sp = (zd*6+yh)*34 + xw
    const _Float16* a0h = xs + ((size_t)((0 * 2 + cih) * SPN) + (td * IHh + th2) * IWh + wl) * 8;
    const _Float16* a0l = xs + ((size_t)((1 * 2 + cih) * SPN) + (td * IHh + th2) * IWh + wl) * 8;
    const _Float16* wfl = wf + (size_t)lane * 8;

    #pragma unroll
    for (int kd = 0; kd < 3; ++kd) {
        #pragma unroll
        for (int kh = 0; kh < 3; ++kh) {
            #pragma unroll
            for (int kw = 0; kw < 3; ++kw) {
                const int tap  = (kd * 3 + kh) * 3 + kw;
                const int aoff = ((kd * IHh + kh) * IWh + kw) * 8;
                half8 Bh = *(const half8*)(wfl + (size_t)(tap * 2 + 0) * 512);
                half8 Bl = *(const half8*)(wfl + (size_t)(tap * 2 + 1) * 512);
                half8 Ah0 = *(const half8*)(a0h + aoff);
                half8 Al0 = *(const half8*)(a0l + aoff);
                acc0 = __builtin_amdgcn_mfma_f32_32x32x16_f16(Ah0, Bh, acc0, 0, 0, 0);
                acc0 = __builtin_amdgcn_mfma_f32_32x32x16_f16(Al0, Bh, acc0, 0, 0, 0);
                acc0 = __builtin_amdgcn_mfma_f32_32x32x16_f16(Ah0, Bl, acc0, 0, 0, 0);
                half8 Ah1 = *(const half8*)(a0h + aoff + IWh * 8);
                half8 Al1 = *(const half8*)(a0l + aoff + IWh * 8);
                acc1 = __builtin_amdgcn_mfma_f32_32x32x16_f16(Ah1, Bh, acc1, 0, 0, 0);
                acc1 = __builtin_amdgcn_mfma_f32_32x32x16_f16(Al1, Bh, acc1, 0, 0, 0);
                acc1 = __builtin_amdgcn_mfma_f32_32x32x16_f16(Ah1, Bl, acc1, 0, 0, 0);
            }
        }
    }

    // ---- epilogue: pointwise norm, then max over couts via LDS scratch ----
    __syncthreads();   // xs no longer needed as input tile; reuse as scratch

    float* sc = (float*)xs + (size_t)wid * (64 * 33);   // 8448 B per wave
    const float bi = bias[wl];
    const float mu = mult[wl];
    const float cf = 1.0f - 1.0f / (float)COUT;

    #pragma unroll
    for (int f = 0; f < 2; ++f) {
        const f32x16 acc = f ? acc1 : acc0;
        #pragma unroll
        for (int r = 0; r < 16; ++r) {
            int row = (r & 3) + 8 * (r >> 2) + 4 * cih;   // verified C/D mapping
            float y = acc[r] + bi;
            float t = y * mu * cf;
            float u = fabsf(t) + EPSF;
            float nr = t * rsqrtf(u);
            float cl = fminf(fmaxf(nr, -1.0f), 1.0f);
            sc[(f * 32 + row) * 33 + wl] = cl * mu;       // bank-conflict-free (stride 33)
        }
    }
    // within-wave LDS RAW: compiler inserts lgkmcnt waits; no cross-wave sharing
    const float* rrow = (float*)xs + (size_t)wid * (64 * 33) + (size_t)lane * 33;
    float v = -INFINITY;
    #pragma unroll
    for (int j = 0; j < 32; ++j) v = fmaxf(v, rrow[j]);

    const int fl = lane >> 5;
    out[(((size_t)b * DD + (d0 + td)) * HH + (h0 + th2 + fl)) * WW + (w0 + wl)] = v;
}

// =====================================================================
// fallback: round-1 fp32 kernel (used only if ws is too small)
// =====================================================================
#define TD 4
#define TH 8
#define TW 8
#define IDf (TD + 2)
#define IHf (TH + 2)
#define IWf (TW + 2)
#define XSF_SIZE (CIN * IDf * IHf * IWf)
#define W_ELEMS (COUT * CIN * 27)

__global__ void transpose_w_kernel(const float* __restrict__ w, float* __restrict__ wt) {
    int i = blockIdx.x * 256 + threadIdx.x;
    if (i < W_ELEMS) {
        int idx = i >> 5;
        int co  = i & 31;
        wt[i] = w[co * (CIN * 27) + idx];
    }
}

__launch_bounds__(256)
__global__ void conv_fused_fp32(const float* __restrict__ x,
                                const float* __restrict__ w,
                                const float* __restrict__ bias,
                                const float* __restrict__ mult,
                                float* __restrict__ out) {
    __shared__ float xsf[XSF_SIZE];
    const int tid = threadIdx.x;
    const int wt_ = blockIdx.x & 15;
    const int ht_ = blockIdx.x >> 4;
    const int dt_ = blockIdx.y;
    const int b   = blockIdx.z;
    const int w0 = wt_ * TW, h0 = ht_ * TH, d0 = dt_ * TD;

    const float* xb = x + (size_t)b * CIN * DD * HH * WW;
    for (int i = tid; i < XSF_SIZE; i += 256) {
        int ci = i / (IDf * IHf * IWf);
        int r  = i % (IDf * IHf * IWf);
        int zd = r / (IHf * IWf);
        int r2 = r % (IHf * IWf);
        int yh = r2 / IWf;
        int xw = r2 % IWf;
        int d = d0 + zd - 1, h = h0 + yh - 1, ww = w0 + xw - 1;
        float v = 0.0f;
        if ((unsigned)d < DD && (unsigned)h < HH && (unsigned)ww < WW)
            v = xb[((size_t)ci * DD + d) * (HH * WW) + h * WW + ww];
        xsf[i] = v;
    }
    __syncthreads();

    const int tw = tid & 7;
    const int th = (tid >> 3) & 7;
    const int td = tid >> 6;

    float acc[COUT];
    #pragma unroll
    for (int co = 0; co < COUT; ++co) acc[co] = 0.0f;

    #pragma unroll 1
    for (int ci = 0; ci < CIN; ++ci) {
        #pragma unroll
        for (int kd = 0; kd < 3; ++kd) {
            #pragma unroll
            for (int kh = 0; kh < 3; ++kh) {
                const float* xrow = &xsf[((ci * IDf + td + kd) * IHf + th + kh) * IWf + tw];
                const float x0 = xrow[0], x1 = xrow[1], x2 = xrow[2];
                const int idx = ci * 27 + kd * 9 + kh * 3;
                const float* wr = w + idx * COUT;
                #pragma unroll
                for (int co = 0; co < COUT; ++co) {
                    acc[co] = fmaf(x0, wr[co], acc[co]);
                    acc[co] = fmaf(x1, wr[COUT + co], acc[co]);
                    acc[co] = fmaf(x2, wr[2 * COUT + co], acc[co]);
                }
            }
        }
    }

    const float cfac = 1.0f - 1.0f / (float)COUT;
    float best = -INFINITY;
    #pragma unroll
    for (int co = 0; co < COUT; ++co) {
        const float m = mult[co];
        const float y = (acc[co] + bias[co]) * m;
        const float t = y * cfac;
        const float nrm = t / sqrtf(fabsf(t) + EPSF);
        const float c = fminf(fmaxf(nrm, -1.0f), 1.0f);
        best = fmaxf(best, c * m);
    }
    out[((size_t)(b * DD + d0 + td) * HH + (h0 + th)) * WW + (w0 + tw)] = best;
}

// =====================================================================
extern "C" void kernel_launch(void* const* d_in, const int* in_sizes, int n_in,
                              void* d_out, int out_size, void* d_ws, size_t ws_size,
                              hipStream_t stream) {
    const float* x    = (const float*)d_in[0];
    const float* wgt  = (const float*)d_in[1];
    const float* bias = (const float*)d_in[2];
    const float* mult = (const float*)d_in[3];
    float* out = (float*)d_out;

    if (ws_size >= WS_NEEDED) {
        _Float16* wf = (_Float16*)d_ws;
        _Float16* xt = wf + WFRAG_HALFS;
        prep_w<<<14, 256, 0, stream>>>(wgt, wf);
        prep_x<<<(B_ * DD * HH * WW) / 256, 256, 0, stream>>>(x, xt);
        dim3 grid(4 * 32, 16, B_);   // (W/32 * H/4, D/2, B)
        conv_mfma<<<grid, 256, 0, stream>>>(xt, wf, bias, mult, out);
    } else if (ws_size >= (size_t)W_ELEMS * sizeof(float)) {
        float* wt = (float*)d_ws;
        transpose_w_kernel<<<(W_ELEMS + 255) / 256, 256, 0, stream>>>(wgt, wt);
        dim3 grid(16 * 16, DD / TD, B_);
        conv_fused_fp32<<<grid, 256, 0, stream>>>(x, wt, bias, mult, out);
    }
}

// Round 4
// 361.625 us; speedup vs baseline: 2.6583x; 1.0774x over previous
//
#include <hip/hip_runtime.h>
#include <math.h>

// ---------------- problem constants ----------------
#define B_    4
#define CIN   16
#define COUT  32
#define DD    32
#define HH    128
#define WW    128
#define EPSF  1e-5f

typedef _Float16 half8 __attribute__((ext_vector_type(8)));
typedef float f32x16 __attribute__((ext_vector_type(16)));

// ws: weight fragments only — 27 taps * 2 planes * 64 lanes * 8 halfs
#define WFRAG_HALFS (27 * 2 * 64 * 8)                 // 27648 halfs = 55296 B
#define WS_NEEDED   ((size_t)WFRAG_HALFS * 2)

// =====================================================================
// pre-pass: weight fragments.
// wf[tap][plane][lane][j] = plane(w[co][ci][tap]), co=lane&31, ci=(lane>>5)*8+j
// plane0 = f16 hi, plane1 = f16 residual.
// =====================================================================
__global__ void prep_w(const float* __restrict__ w, _Float16* __restrict__ wf) {
    int t = blockIdx.x * 256 + threadIdx.x;
    if (t >= 27 * 2 * 64) return;
    int lane = t & 63;
    int pp = t >> 6;
    int tap = pp >> 1, plane = pp & 1;
    int co = lane & 31, cih = lane >> 5;
    half8 o;
    #pragma unroll
    for (int j = 0; j < 8; ++j) {
        int ci = cih * 8 + j;
        float v = w[(co * CIN + ci) * 27 + tap];
        _Float16 hi = (_Float16)v;
        o[j] = plane ? (_Float16)(v - (float)hi) : hi;
    }
    *(half8*)(wf + (size_t)t * 8) = o;
}

// =====================================================================
// main conv kernel: implicit GEMM, mfma_f32_32x32x16_f16, split-f16 x3.
// Reads fp32 x (NCDHW) directly; hi/lo split happens during LDS staging.
// Block tile: (TD=2, TH=4, TW=32); 4 waves: wave=(td, th2). Halo LDS:
// [pc(4)][sp(4*6*34)][8] halfs = 52224 B. pc = plane*2 + cihalf.
// Inner loop: kh-row sharing between the wave's two output rows cuts
// A-reads to 72 ds_read_b128 / 162 MFMAs per wave.
// =====================================================================
#define IDh 4
#define IHh 6
#define IWh 34
#define SPN (IDh * IHh * IWh)     // 816
#define XS_HALFS (4 * SPN * 8)    // 26112 halfs = 52224 B

__launch_bounds__(256, 3)
__global__ void conv_mfma(const float* __restrict__ x,
                          const _Float16* __restrict__ wf,
                          const float* __restrict__ bias,
                          const float* __restrict__ mult,
                          float* __restrict__ out) {
    __shared__ _Float16 xs[XS_HALFS];

    const int tid  = threadIdx.x;
    const int lane = tid & 63;
    const int wid  = tid >> 6;

    const int wt = blockIdx.x & 3;     // W/32
    const int ht = blockIdx.x >> 2;    // H/4
    const int dt = blockIdx.y;         // D/2
    const int b  = blockIdx.z;
    const int w0 = wt * 32, h0 = ht * 4, d0 = dt * 2;

    // ---- stage fp32 halo -> split-f16 LDS (hi plane + residual plane) ----
    for (int i = tid; i < 2 * SPN; i += 256) {
        int cih = (i >= SPN) ? 1 : 0;
        int sp  = i - cih * SPN;
        int zd  = sp / (IHh * IWh);
        int r2  = sp - zd * (IHh * IWh);
        int yh  = r2 / IWh;
        int col = r2 - yh * IWh;
        int d = d0 + zd - 1, h = h0 + yh - 1, w = w0 + col - 1;
        half8 hi = {}, lo = {};
        if (((unsigned)d < DD) & ((unsigned)h < HH) & ((unsigned)w < WW)) {
            const float* gx = x + ((size_t)(b * CIN + cih * 8) * DD + d) * (HH * WW) + h * WW + w;
            #pragma unroll
            for (int j = 0; j < 8; ++j) {
                float v = gx[(size_t)j * DD * HH * WW];
                _Float16 hv = (_Float16)v;
                hi[j] = hv;
                lo[j] = (_Float16)(v - (float)hv);
            }
        }
        *(half8*)&xs[(size_t)(cih * SPN + sp) * 8]       = hi;
        *(half8*)&xs[(size_t)((2 + cih) * SPN + sp) * 8] = lo;
    }
    __syncthreads();

    const int td  = wid >> 1;
    const int th2 = (wid & 1) * 2;
    const int cih = lane >> 5;
    const int wl  = lane & 31;

    f32x16 acc0 = {};
    f32x16 acc1 = {};

    const _Float16* aH  = xs + (size_t)(cih * SPN) * 8;
    const _Float16* aL  = xs + (size_t)((2 + cih) * SPN) * 8;
    const _Float16* wfl = wf + (size_t)lane * 8;

    half8 Ah0, Ah1, Ah2, Al0, Al1, Al2;     // current input row, 3 kw windows
    half8 Xh0, Xh1, Xh2, Xl0, Xl1, Xl2;     // B rolling slot X
    half8 Yh0, Yh1, Yh2, Yl0, Yl1, Yl2;     // B rolling slot Y

#define LDB(BH0, BH1, BH2, BL0, BL1, BL2, KH) do {                         \
        const int t0 = (kd * 3 + (KH)) * 3;                                \
        BH0 = *(const half8*)(wfl + (size_t)((t0 + 0) * 2 + 0) * 512);     \
        BL0 = *(const half8*)(wfl + (size_t)((t0 + 0) * 2 + 1) * 512);     \
        BH1 = *(const half8*)(wfl + (size_t)((t0 + 1) * 2 + 0) * 512);     \
        BL1 = *(const half8*)(wfl + (size_t)((t0 + 1) * 2 + 1) * 512);     \
        BH2 = *(const half8*)(wfl + (size_t)((t0 + 2) * 2 + 0) * 512);     \
        BL2 = *(const half8*)(wfl + (size_t)((t0 + 2) * 2 + 1) * 512);     \
    } while (0)

#define LDA(R) do {                                                        \
        const int spb = ((td + kd) * IHh + th2 + (R)) * IWh + wl;          \
        Ah0 = *(const half8*)(aH + (size_t)(spb + 0) * 8);                 \
        Ah1 = *(const half8*)(aH + (size_t)(spb + 1) * 8);                 \
        Ah2 = *(const half8*)(aH + (size_t)(spb + 2) * 8);                 \
        Al0 = *(const half8*)(aL + (size_t)(spb + 0) * 8);                 \
        Al1 = *(const half8*)(aL + (size_t)(spb + 1) * 8);                 \
        Al2 = *(const half8*)(aL + (size_t)(spb + 2) * 8);                 \
    } while (0)

#define DOT(ACC, BH0, BH1, BH2, BL0, BL1, BL2) do {                        \
        ACC = __builtin_amdgcn_mfma_f32_32x32x16_f16(Ah0, BH0, ACC, 0, 0, 0); \
        ACC = __builtin_amdgcn_mfma_f32_32x32x16_f16(Al0, BH0, ACC, 0, 0, 0); \
        ACC = __builtin_amdgcn_mfma_f32_32x32x16_f16(Ah0, BL0, ACC, 0, 0, 0); \
        ACC = __builtin_amdgcn_mfma_f32_32x32x16_f16(Ah1, BH1, ACC, 0, 0, 0); \
        ACC = __builtin_amdgcn_mfma_f32_32x32x16_f16(Al1, BH1, ACC, 0, 0, 0); \
        ACC = __builtin_amdgcn_mfma_f32_32x32x16_f16(Ah1, BL1, ACC, 0, 0, 0); \
        ACC = __builtin_amdgcn_mfma_f32_32x32x16_f16(Ah2, BH2, ACC, 0, 0, 0); \
        ACC = __builtin_amdgcn_mfma_f32_32x32x16_f16(Al2, BH2, ACC, 0, 0, 0); \
        ACC = __builtin_amdgcn_mfma_f32_32x32x16_f16(Ah2, BL2, ACC, 0, 0, 0); \
    } while (0)

    #pragma unroll
    for (int kd = 0; kd < 3; ++kd) {
        // r=0: row th2+0 -> acc0 kh=0
        LDB(Xh0, Xh1, Xh2, Xl0, Xl1, Xl2, 0);
        LDA(0);
        DOT(acc0, Xh0, Xh1, Xh2, Xl0, Xl1, Xl2);
        // r=1: row th2+1 -> acc0 kh=1, acc1 kh=0
        LDB(Yh0, Yh1, Yh2, Yl0, Yl1, Yl2, 1);
        LDA(1);
        DOT(acc0, Yh0, Yh1, Yh2, Yl0, Yl1, Yl2);
        DOT(acc1, Xh0, Xh1, Xh2, Xl0, Xl1, Xl2);
        // r=2: row th2+2 -> acc0 kh=2, acc1 kh=1   (slot X now holds kh=2)
        LDB(Xh0, Xh1, Xh2, Xl0, Xl1, Xl2, 2);
        LDA(2);
        DOT(acc0, Xh0, Xh1, Xh2, Xl0, Xl1, Xl2);
        DOT(acc1, Yh0, Yh1, Yh2, Yl0, Yl1, Yl2);
        // r=3: row th2+3 -> acc1 kh=2
        LDA(3);
        DOT(acc1, Xh0, Xh1, Xh2, Xl0, Xl1, Xl2);
    }
#undef LDB
#undef LDA
#undef DOT

    // ---- epilogue: pointwise norm, then max over couts via LDS scratch ----
    __syncthreads();   // input tile no longer needed; reuse xs as scratch

    float* sc = (float*)xs + (size_t)wid * (64 * 33);
    const float bi = bias[wl];
    const float mu = mult[wl];
    const float cf = 1.0f - 1.0f / (float)COUT;

    #pragma unroll
    for (int f = 0; f < 2; ++f) {
        const f32x16 acc = f ? acc1 : acc0;
        #pragma unroll
        for (int r = 0; r < 16; ++r) {
            int row = (r & 3) + 8 * (r >> 2) + 4 * cih;   // verified C/D mapping
            float y = acc[r] + bi;
            float t = y * mu * cf;
            float u = fabsf(t) + EPSF;
            float nr = t * rsqrtf(u);
            float cl = fminf(fmaxf(nr, -1.0f), 1.0f);
            sc[(f * 32 + row) * 33 + wl] = cl * mu;       // stride 33: conflict-free
        }
    }
    const float* rrow = (float*)xs + (size_t)wid * (64 * 33) + (size_t)lane * 33;
    float v = -INFINITY;
    #pragma unroll
    for (int j = 0; j < 32; ++j) v = fmaxf(v, rrow[j]);

    const int fl = lane >> 5;
    out[(((size_t)b * DD + (d0 + td)) * HH + (h0 + th2 + fl)) * WW + (w0 + wl)] = v;
}

// =====================================================================
// fallback: fp32 vector kernel, untransposed weights (zero ws required)
// =====================================================================
#define TDf 4
#define THf 8
#define TWf 8
#define IDf (TDf + 2)
#define IHf (THf + 2)
#define IWf (TWf + 2)
#define XSF_SIZE (CIN * IDf * IHf * IWf)

__launch_bounds__(256)
__global__ void conv_fused_fp32(const float* __restrict__ x,
                                const float* __restrict__ w,
                                const float* __restrict__ bias,
                                const float* __restrict__ mult,
                                float* __restrict__ out) {
    __shared__ float xsf[XSF_SIZE];
    const int tid = threadIdx.x;
    const int wt_ = blockIdx.x & 15;
    const int ht_ = blockIdx.x >> 4;
    const int dt_ = blockIdx.y;
    const int b   = blockIdx.z;
    const int w0 = wt_ * TWf, h0 = ht_ * THf, d0 = dt_ * TDf;

    const float* xb = x + (size_t)b * CIN * DD * HH * WW;
    for (int i = tid; i < XSF_SIZE; i += 256) {
        int ci = i / (IDf * IHf * IWf);
        int r  = i % (IDf * IHf * IWf);
        int zd = r / (IHf * IWf);
        int r2 = r % (IHf * IWf);
        int yh = r2 / IWf;
        int xw = r2 % IWf;
        int d = d0 + zd - 1, h = h0 + yh - 1, ww = w0 + xw - 1;
        float v = 0.0f;
        if ((unsigned)d < DD && (unsigned)h < HH && (unsigned)ww < WW)
            v = xb[((size_t)ci * DD + d) * (HH * WW) + h * WW + ww];
        xsf[i] = v;
    }
    __syncthreads();

    const int tw = tid & 7;
    const int th = (tid >> 3) & 7;
    const int td = tid >> 6;

    float acc[COUT];
    #pragma unroll
    for (int co = 0; co < COUT; ++co) acc[co] = 0.0f;

    #pragma unroll 1
    for (int ci = 0; ci < CIN; ++ci) {
        #pragma unroll
        for (int kd = 0; kd < 3; ++kd) {
            #pragma unroll
            for (int kh = 0; kh < 3; ++kh) {
                const float* xrow = &xsf[((ci * IDf + td + kd) * IHf + th + kh) * IWf + tw];
                const float x0 = xrow[0], x1 = xrow[1], x2 = xrow[2];
                const int idx = ci * 27 + kd * 9 + kh * 3;
                #pragma unroll
                for (int co = 0; co < COUT; ++co) {
                    const float* wr = w + co * (CIN * 27) + idx;
                    acc[co] = fmaf(x0, wr[0], acc[co]);
                    acc[co] = fmaf(x1, wr[1], acc[co]);
                    acc[co] = fmaf(x2, wr[2], acc[co]);
                }
            }
        }
    }

    const float cfac = 1.0f - 1.0f / (float)COUT;
    float best = -INFINITY;
    #pragma unroll
    for (int co = 0; co < COUT; ++co) {
        const float m = mult[co];
        const float y = (acc[co] + bias[co]) * m;
        const float t = y * cfac;
        const float nrm = t / sqrtf(fabsf(t) + EPSF);
        const float c = fminf(fmaxf(nrm, -1.0f), 1.0f);
        best = fmaxf(best, c * m);
    }
    out[((size_t)(b * DD + d0 + td) * HH + (h0 + th)) * WW + (w0 + tw)] = best;
}

// =====================================================================
extern "C" void kernel_launch(void* const* d_in, const int* in_sizes, int n_in,
                              void* d_out, int out_size, void* d_ws, size_t ws_size,
                              hipStream_t stream) {
    const float* x    = (const float*)d_in[0];
    const float* wgt  = (const float*)d_in[1];
    const float* bias = (const float*)d_in[2];
    const float* mult = (const float*)d_in[3];
    float* out = (float*)d_out;

    if (ws_size >= WS_NEEDED) {
        _Float16* wf = (_Float16*)d_ws;
        prep_w<<<14, 256, 0, stream>>>(wgt, wf);
        dim3 grid(4 * 32, 16, B_);   // (W/32 * H/4, D/2, B)
        conv_mfma<<<grid, 256, 0, stream>>>(x, wf, bias, mult, out);
    } else {
        dim3 grid(16 * 16, DD / TDf, B_);
        conv_fused_fp32<<<grid, 256, 0, stream>>>(x, wgt, bias, mult, out);
    }
}

// Round 6
// 331.882 us; speedup vs baseline: 2.8966x; 1.0896x over previous
//
#include <hip/hip_runtime.h>
#include <math.h>

// ---------------- problem constants ----------------
#define B_    4
#define CIN   16
#define COUT  32
#define DD    32
#define HH    128
#define WW    128
#define EPSF  1e-5f

typedef _Float16 half8 __attribute__((ext_vector_type(8)));
typedef __fp16 fp16x2 __attribute__((ext_vector_type(2)));   // cvt_pkrtz return type
typedef float f32x16 __attribute__((ext_vector_type(16)));

// ws: weight fragments only — 27 taps * 2 planes * 64 lanes * 8 halfs
#define WFRAG_HALFS (27 * 2 * 64 * 8)                 // 27648 halfs = 55296 B
#define WS_NEEDED   ((size_t)WFRAG_HALFS * 2)

// =====================================================================
// pre-pass: weight fragments.
// wf[tap][plane][lane][j] = plane(w[co][ci][tap]), co=lane&31, ci=(lane>>5)*8+j
// plane0 = f16 hi, plane1 = f16 residual.
// =====================================================================
__global__ void prep_w(const float* __restrict__ w, _Float16* __restrict__ wf) {
    int t = blockIdx.x * 256 + threadIdx.x;
    if (t >= 27 * 2 * 64) return;
    int lane = t & 63;
    int pp = t >> 6;
    int tap = pp >> 1, plane = pp & 1;
    int co = lane & 31, cih = lane >> 5;
    half8 o;
    #pragma unroll
    for (int j = 0; j < 8; ++j) {
        int ci = cih * 8 + j;
        float v = w[(co * CIN + ci) * 27 + tap];
        _Float16 hi = (_Float16)v;
        o[j] = plane ? (_Float16)(v - (float)hi) : hi;
    }
    *(half8*)(wf + (size_t)t * 8) = o;
}

// =====================================================================
// main conv kernel: implicit GEMM, mfma_f32_32x32x16_f16, split-f16 x3.
// Reads fp32 x (NCDHW); hi/lo split via cvt_pkrtz during LDS staging.
// Block tile: (TD=4, TH=4, TW=32), 512 threads = 8 waves: wave=(td, th2).
// Halo LDS: [pc(4)][sp(6*6*34)][8] halfs = 78336 B -> 2 blocks/CU.
// Per wave: 2 accs (rows th2, th2+1), kh-row sharing: 72 ds_read_b128,
// 162 MFMAs.
// =====================================================================
#define IDh 6
#define IHh 6
#define IWh 34
#define SPN (IDh * IHh * IWh)     // 1224
#define XS_HALFS (4 * SPN * 8)    // 39168 halfs = 78336 B

__launch_bounds__(512, 4)
__global__ void conv_mfma(const float* __restrict__ x,
                          const _Float16* __restrict__ wf,
                          const float* __restrict__ bias,
                          const float* __restrict__ mult,
                          float* __restrict__ out) {
    __shared__ _Float16 xs[XS_HALFS];

    const int tid  = threadIdx.x;
    const int lane = tid & 63;
    const int wid  = tid >> 6;

    const int wt = blockIdx.x & 3;     // W/32
    const int ht = blockIdx.x >> 2;    // H/4
    const int dt = blockIdx.y;         // D/4
    const int b  = blockIdx.z;
    const int w0 = wt * 32, h0 = ht * 4, d0 = dt * 4;

    // ---- stage fp32 halo -> split-f16 LDS (hi plane + residual plane) ----
    for (int i = tid; i < 2 * SPN; i += 512) {
        int cih = (i >= SPN) ? 1 : 0;
        int sp  = i - cih * SPN;
        int zd  = sp / (IHh * IWh);
        int r2  = sp - zd * (IHh * IWh);
        int yh  = r2 / IWh;
        int col = r2 - yh * IWh;
        int d = d0 + zd - 1, h = h0 + yh - 1, w = w0 + col - 1;
        half8 hi = {}, lo = {};
        if (((unsigned)d < DD) & ((unsigned)h < HH) & ((unsigned)w < WW)) {
            const float* gx = x + ((size_t)(b * CIN + cih * 8) * DD + d) * (HH * WW) + h * WW + w;
            float v[8];
            #pragma unroll
            for (int j = 0; j < 8; ++j) v[j] = gx[(size_t)j * DD * HH * WW];
            #pragma unroll
            for (int p = 0; p < 4; ++p) {
                fp16x2 hp = __builtin_amdgcn_cvt_pkrtz(v[2 * p], v[2 * p + 1]);
                float h0f = (float)hp[0], h1f = (float)hp[1];
                fp16x2 lp = __builtin_amdgcn_cvt_pkrtz(v[2 * p] - h0f, v[2 * p + 1] - h1f);
                hi[2 * p] = (_Float16)hp[0]; hi[2 * p + 1] = (_Float16)hp[1];
                lo[2 * p] = (_Float16)lp[0]; lo[2 * p + 1] = (_Float16)lp[1];
            }
        }
        *(half8*)&xs[(size_t)(cih * SPN + sp) * 8]       = hi;
        *(half8*)&xs[(size_t)((2 + cih) * SPN + sp) * 8] = lo;
    }
    __syncthreads();

    const int td  = wid >> 1;          // 0..3
    const int th2 = (wid & 1) * 2;     // 0 or 2
    const int cih = lane >> 5;
    const int wl  = lane & 31;

    f32x16 acc0 = {};
    f32x16 acc1 = {};

    const _Float16* aH  = xs + (size_t)(cih * SPN) * 8;
    const _Float16* aL  = xs + (size_t)((2 + cih) * SPN) * 8;
    const _Float16* wfl = wf + (size_t)lane * 8;

    half8 Ah0, Ah1, Ah2, Al0, Al1, Al2;     // current input row, 3 kw windows
    half8 Xh0, Xh1, Xh2, Xl0, Xl1, Xl2;     // B rolling slot X
    half8 Yh0, Yh1, Yh2, Yl0, Yl1, Yl2;     // B rolling slot Y

#define LDB(BH0, BH1, BH2, BL0, BL1, BL2, KH) do {                         \
        const int t0 = (kd * 3 + (KH)) * 3;                                \
        BH0 = *(const half8*)(wfl + (size_t)((t0 + 0) * 2 + 0) * 512);     \
        BL0 = *(const half8*)(wfl + (size_t)((t0 + 0) * 2 + 1) * 512);     \
        BH1 = *(const half8*)(wfl + (size_t)((t0 + 1) * 2 + 0) * 512);     \
        BL1 = *(const half8*)(wfl + (size_t)((t0 + 1) * 2 + 1) * 512);     \
        BH2 = *(const half8*)(wfl + (size_t)((t0 + 2) * 2 + 0) * 512);     \
        BL2 = *(const half8*)(wfl + (size_t)((t0 + 2) * 2 + 1) * 512);     \
    } while (0)

#define LDA(R) do {                                                        \
        const int spb = ((td + kd) * IHh + th2 + (R)) * IWh + wl;          \
        Ah0 = *(const half8*)(aH + (size_t)(spb + 0) * 8);                 \
        Ah1 = *(const half8*)(aH + (size_t)(spb + 1) * 8);                 \
        Ah2 = *(const half8*)(aH + (size_t)(spb + 2) * 8);                 \
        Al0 = *(const half8*)(aL + (size_t)(spb + 0) * 8);                 \
        Al1 = *(const half8*)(aL + (size_t)(spb + 1) * 8);                 \
        Al2 = *(const half8*)(aL + (size_t)(spb + 2) * 8);                 \
    } while (0)

#define DOT(ACC, BH0, BH1, BH2, BL0, BL1, BL2) do {                        \
        ACC = __builtin_amdgcn_mfma_f32_32x32x16_f16(Ah0, BH0, ACC, 0, 0, 0); \
        ACC = __builtin_amdgcn_mfma_f32_32x32x16_f16(Al0, BH0, ACC, 0, 0, 0); \
        ACC = __builtin_amdgcn_mfma_f32_32x32x16_f16(Ah0, BL0, ACC, 0, 0, 0); \
        ACC = __builtin_amdgcn_mfma_f32_32x32x16_f16(Ah1, BH1, ACC, 0, 0, 0); \
        ACC = __builtin_amdgcn_mfma_f32_32x32x16_f16(Al1, BH1, ACC, 0, 0, 0); \
        ACC = __builtin_amdgcn_mfma_f32_32x32x16_f16(Ah1, BL1, ACC, 0, 0, 0); \
        ACC = __builtin_amdgcn_mfma_f32_32x32x16_f16(Ah2, BH2, ACC, 0, 0, 0); \
        ACC = __builtin_amdgcn_mfma_f32_32x32x16_f16(Al2, BH2, ACC, 0, 0, 0); \
        ACC = __builtin_amdgcn_mfma_f32_32x32x16_f16(Ah2, BL2, ACC, 0, 0, 0); \
    } while (0)

    #pragma unroll
    for (int kd = 0; kd < 3; ++kd) {
        // r=0: row th2+0 -> acc0 kh=0
        LDB(Xh0, Xh1, Xh2, Xl0, Xl1, Xl2, 0);
        LDA(0);
        DOT(acc0, Xh0, Xh1, Xh2, Xl0, Xl1, Xl2);
        // r=1: row th2+1 -> acc0 kh=1, acc1 kh=0
        LDB(Yh0, Yh1, Yh2, Yl0, Yl1, Yl2, 1);
        LDA(1);
        DOT(acc0, Yh0, Yh1, Yh2, Yl0, Yl1, Yl2);
        DOT(acc1, Xh0, Xh1, Xh2, Xl0, Xl1, Xl2);
        // r=2: row th2+2 -> acc0 kh=2, acc1 kh=1   (slot X now holds kh=2)
        LDB(Xh0, Xh1, Xh2, Xl0, Xl1, Xl2, 2);
        LDA(2);
        DOT(acc0, Xh0, Xh1, Xh2, Xl0, Xl1, Xl2);
        DOT(acc1, Yh0, Yh1, Yh2, Yl0, Yl1, Yl2);
        // r=3: row th2+3 -> acc1 kh=2
        LDA(3);
        DOT(acc1, Xh0, Xh1, Xh2, Xl0, Xl1, Xl2);
    }
#undef LDB
#undef LDA
#undef DOT

    // ---- epilogue: pointwise norm, then max over couts via LDS scratch ----
    __syncthreads();   // input tile no longer needed; reuse xs as scratch

    float* sc = (float*)xs + (size_t)wid * (64 * 33);   // 8 waves * 8448 B = 67.6 KB
    const float mu = mult[wl];
    const float m1 = mu * (1.0f - 1.0f / (float)COUT);
    const float b1 = bias[wl] * m1;

    #pragma unroll
    for (int f = 0; f < 2; ++f) {
        const f32x16 acc = f ? acc1 : acc0;
        #pragma unroll
        for (int r = 0; r < 16; ++r) {
            int row = (r & 3) + 8 * (r >> 2) + 4 * cih;   // verified C/D mapping
            float t = fmaf(acc[r], m1, b1);
            float u = fabsf(t) + EPSF;
            float nr = t * rsqrtf(u);
            float cl = fminf(fmaxf(nr, -1.0f), 1.0f);     // -> v_med3
            sc[(f * 32 + row) * 33 + wl] = cl * mu;       // stride 33: conflict-free
        }
    }
    const float* rrow = (float*)xs + (size_t)wid * (64 * 33) + (size_t)lane * 33;
    float v = -INFINITY;
    #pragma unroll
    for (int j = 0; j < 32; ++j) v = fmaxf(v, rrow[j]);

    const int fl = lane >> 5;
    out[(((size_t)b * DD + (d0 + td)) * HH + (h0 + th2 + fl)) * WW + (w0 + wl)] = v;
}

// =====================================================================
// fallback: fp32 vector kernel (zero ws required)
// =====================================================================
#define TDf 4
#define THf 8
#define TWf 8
#define IDf (TDf + 2)
#define IHf (THf + 2)
#define IWf (TWf + 2)
#define XSF_SIZE (CIN * IDf * IHf * IWf)

__launch_bounds__(256)
__global__ void conv_fused_fp32(const float* __restrict__ x,
                                const float* __restrict__ w,
                                const float* __restrict__ bias,
                                const float* __restrict__ mult,
                                float* __restrict__ out) {
    __shared__ float xsf[XSF_SIZE];
    const int tid = threadIdx.x;
    const int wt_ = blockIdx.x & 15;
    const int ht_ = blockIdx.x >> 4;
    const int dt_ = blockIdx.y;
    const int b   = blockIdx.z;
    const int w0 = wt_ * TWf, h0 = ht_ * THf, d0 = dt_ * TDf;

    const float* xb = x + (size_t)b * CIN * DD * HH * WW;
    for (int i = tid; i < XSF_SIZE; i += 256) {
        int ci = i / (IDf * IHf * IWf);
        int r  = i % (IDf * IHf * IWf);
        int zd = r / (IHf * IWf);
        int r2 = r % (IHf * IWf);
        int yh = r2 / IWf;
        int xw = r2 % IWf;
        int d = d0 + zd - 1, h = h0 + yh - 1, ww = w0 + xw - 1;
        float v = 0.0f;
        if ((unsigned)d < DD && (unsigned)h < HH && (unsigned)ww < WW)
            v = xb[((size_t)ci * DD + d) * (HH * WW) + h * WW + ww];
        xsf[i] = v;
    }
    __syncthreads();

    const int tw = tid & 7;
    const int th = (tid >> 3) & 7;
    const int td = tid >> 6;

    float acc[COUT];
    #pragma unroll
    for (int co = 0; co < COUT; ++co) acc[co] = 0.0f;

    #pragma unroll 1
    for (int ci = 0; ci < CIN; ++ci) {
        #pragma unroll
        for (int kd = 0; kd < 3; ++kd) {
            #pragma unroll
            for (int kh = 0; kh < 3; ++kh) {
                const float* xrow = &xsf[((ci * IDf + td + kd) * IHf + th + kh) * IWf + tw];
                const float x0 = xrow[0], x1 = xrow[1], x2 = xrow[2];
                const int idx = ci * 27 + kd * 9 + kh * 3;
                #pragma unroll
                for (int co = 0; co < COUT; ++co) {
                    const float* wr = w + co * (CIN * 27) + idx;
                    acc[co] = fmaf(x0, wr[0], acc[co]);
                    acc[co] = fmaf(x1, wr[1], acc[co]);
                    acc[co] = fmaf(x2, wr[2], acc[co]);
                }
            }
        }
    }

    const float cfac = 1.0f - 1.0f / (float)COUT;
    float best = -INFINITY;
    #pragma unroll
    for (int co = 0; co < COUT; ++co) {
        const float m = mult[co];
        const float y = (acc[co] + bias[co]) * m;
        const float t = y * cfac;
        const float nrm = t / sqrtf(fabsf(t) + EPSF);
        const float c = fminf(fmaxf(nrm, -1.0f), 1.0f);
        best = fmaxf(best, c * m);
    }
    out[((size_t)(b * DD + d0 + td) * HH + (h0 + th)) * WW + (w0 + tw)] = best;
}

// =====================================================================
extern "C" void kernel_launch(void* const* d_in, const int* in_sizes, int n_in,
                              void* d_out, int out_size, void* d_ws, size_t ws_size,
                              hipStream_t stream) {
    const float* x    = (const float*)d_in[0];
    const float* wgt  = (const float*)d_in[1];
    const float* bias = (const float*)d_in[2];
    const float* mult = (const float*)d_in[3];
    float* out = (float*)d_out;

    if (ws_size >= WS_NEEDED) {
        _Float16* wf = (_Float16*)d_ws;
        prep_w<<<14, 256, 0, stream>>>(wgt, wf);
        dim3 grid(4 * 32, 8, B_);   // (W/32 * H/4, D/4, B)
        conv_mfma<<<grid, 512, 0, stream>>>(x, wf, bias, mult, out);
    } else {
        dim3 grid(16 * 16, DD / TDf, B_);
        conv_fused_fp32<<<grid, 256, 0, stream>>>(x, wgt, bias, mult, out);
    }
}